// Round 1
// baseline (406.169 us; speedup 1.0000x reference)
//
#include <hip/hip_runtime.h>
#include <hip/hip_bf16.h>

#define K_DIM 4096
#define N_DIM 4096
#define R_DIM 16
#define SCALING_F 2.0f

#define BM 128
#define BN 128
#define BK 32

typedef __attribute__((ext_vector_type(8))) short bf16x8;
typedef __attribute__((ext_vector_type(4))) float f32x4;

__device__ __forceinline__ ushort f2bf(float f) {
  union { float f; unsigned u; } v; v.f = f;
  unsigned u = v.u;
  u += 0x7FFF + ((u >> 16) & 1);   // round-to-nearest-even
  return (ushort)(u >> 16);
}

// ---- pre-pass 1: x (fp32) -> bf16 ----
__global__ void convert_x_kernel(const float* __restrict__ x,
                                 ushort* __restrict__ xb, long n4) {
  long i = (long)blockIdx.x * blockDim.x + threadIdx.x;
  long stride = (long)gridDim.x * blockDim.x;
  for (; i < n4; i += stride) {
    long idx = i * 4;
    float4 v = *(const float4*)(x + idx);
    ushort4 o;
    o.x = f2bf(v.x); o.y = f2bf(v.y); o.z = f2bf(v.z); o.w = f2bf(v.w);
    *(ushort4*)(xb + idx) = o;
  }
}

// ---- pre-pass 2: W_eff = W + 2.0 * (lora_B @ lora_A), cast to bf16 ----
__global__ void fold_w_kernel(const float* __restrict__ W,
                              const float* __restrict__ A,
                              const float* __restrict__ Bl,
                              ushort* __restrict__ wb) {
  int o = blockIdx.x;  // output row (0..N_DIM-1)
  float breg[R_DIM];
#pragma unroll
  for (int r = 0; r < R_DIM; ++r) breg[r] = Bl[o * R_DIM + r] * SCALING_F;
  for (int d0 = threadIdx.x * 4; d0 < K_DIM; d0 += blockDim.x * 4) {
    float4 w = *(const float4*)(W + (size_t)o * K_DIM + d0);
    float a0 = w.x, a1 = w.y, a2 = w.z, a3 = w.w;
#pragma unroll
    for (int r = 0; r < R_DIM; ++r) {
      float4 a = *(const float4*)(A + (size_t)r * K_DIM + d0);
      a0 += breg[r] * a.x; a1 += breg[r] * a.y;
      a2 += breg[r] * a.z; a3 += breg[r] * a.w;
    }
    ushort4 ob;
    ob.x = f2bf(a0); ob.y = f2bf(a1); ob.z = f2bf(a2); ob.w = f2bf(a3);
    *(ushort4*)(wb + (size_t)o * K_DIM + d0) = ob;
  }
}

// ---- main GEMM: out[m][n] = sum_k xb[m][k]*wb[n][k] + bias[n] ----
// m97-structure: 128x128 tile, BK=32, 4 waves (2x2), 16x16x32 bf16 MFMA,
// global_load_lds width=16 staging, fp32 accumulate + bias epilogue.
__global__ __launch_bounds__(256) void gemm_lora_kernel(
    const ushort* __restrict__ Ab, const ushort* __restrict__ Bb,
    const float* __restrict__ bias, float* __restrict__ C) {
  __shared__ ushort As[BM * BK];  // 8 KB, rows of 64 B
  __shared__ ushort Bs[BN * BK];  // 8 KB

  const int tid = threadIdx.x;
  const int wave = tid >> 6;
  const int lane = tid & 63;

  const int bm = blockIdx.x / (N_DIM / BN);
  const int bn = blockIdx.x % (N_DIM / BN);

  const int wm = wave >> 1;  // 0..1
  const int wn = wave & 1;   // 0..1

  f32x4 acc[4][4];
#pragma unroll
  for (int m = 0; m < 4; ++m)
#pragma unroll
    for (int n = 0; n < 4; ++n) acc[m][n] = (f32x4){0.f, 0.f, 0.f, 0.f};

  // staging geometry: lane writes LDS byte [i*4096 + wave*1024 + lane*16]
  // -> row = i*64 + wave*16 + lane/4, col(bf16) = (lane&3)*8
  const int srow = wave * 16 + (lane >> 2);
  const int scol = (lane & 3) * 8;
  const ushort* agp = Ab + (size_t)(bm * BM + srow) * K_DIM + scol;
  const ushort* bgp = Bb + (size_t)(bn * BN + srow) * K_DIM + scol;

  const int fr = lane & 15;  // fragment row (A) / row (B) / C col
  const int fq = lane >> 4;  // 0..3

  for (int kt = 0; kt < K_DIM / BK; ++kt) {
#pragma unroll
    for (int i = 0; i < 2; ++i) {
      __builtin_amdgcn_global_load_lds(
          (const __attribute__((address_space(1))) void*)(agp + (size_t)i * 64 * K_DIM),
          (__attribute__((address_space(3))) void*)((char*)As + i * 4096 + wave * 1024),
          16, 0, 0);
      __builtin_amdgcn_global_load_lds(
          (const __attribute__((address_space(1))) void*)(bgp + (size_t)i * 64 * K_DIM),
          (__attribute__((address_space(3))) void*)((char*)Bs + i * 4096 + wave * 1024),
          16, 0, 0);
    }
    __syncthreads();  // compiler emits vmcnt(0) drain before barrier

    bf16x8 a_frag[4], b_frag[4];
#pragma unroll
    for (int m = 0; m < 4; ++m)
      a_frag[m] = *(const bf16x8*)(As + (wm * 64 + m * 16 + fr) * BK + fq * 8);
#pragma unroll
    for (int n = 0; n < 4; ++n)
      b_frag[n] = *(const bf16x8*)(Bs + (wn * 64 + n * 16 + fr) * BK + fq * 8);
#pragma unroll
    for (int m = 0; m < 4; ++m)
#pragma unroll
      for (int n = 0; n < 4; ++n)
        acc[m][n] = __builtin_amdgcn_mfma_f32_16x16x32_bf16(
            a_frag[m], b_frag[n], acc[m][n], 0, 0, 0);

    __syncthreads();
    agp += BK;
    bgp += BK;
  }

  // epilogue: C/D layout col=lane&15, row=(lane>>4)*4+reg  [measured m89/m91]
  const int ccol0 = bn * BN + wn * 64 + fr;
  float bv[4];
#pragma unroll
  for (int n = 0; n < 4; ++n) bv[n] = bias[ccol0 + n * 16];

  const int crow0 = bm * BM + wm * 64 + fq * 4;
#pragma unroll
  for (int m = 0; m < 4; ++m)
#pragma unroll
    for (int n = 0; n < 4; ++n)
#pragma unroll
      for (int v = 0; v < 4; ++v) {
        int row = crow0 + m * 16 + v;
        C[(size_t)row * N_DIM + ccol0 + n * 16] = acc[m][n][v] + bv[n];
      }
}

extern "C" void kernel_launch(void* const* d_in, const int* in_sizes, int n_in,
                              void* d_out, int out_size, void* d_ws, size_t ws_size,
                              hipStream_t stream) {
  const float* x  = (const float*)d_in[0];   // [M, K]
  const float* W  = (const float*)d_in[1];   // [N, K]
  const float* b  = (const float*)d_in[2];   // [N]
  const float* lA = (const float*)d_in[3];   // [R, K]
  const float* lB = (const float*)d_in[4];   // [N, R]
  float* out = (float*)d_out;                // [M, N]

  const int M = in_sizes[0] / K_DIM;  // 8192

  // workspace: x_bf16 (M*K*2 = 64 MB) then W_eff_bf16 (N*K*2 = 32 MB)
  ushort* xb = (ushort*)d_ws;
  ushort* wb = xb + (size_t)M * K_DIM;

  long n4 = (long)M * K_DIM / 4;
  convert_x_kernel<<<2048, 256, 0, stream>>>(x, xb, n4);
  fold_w_kernel<<<N_DIM, 256, 0, stream>>>(W, lA, lB, wb);
  gemm_lora_kernel<<<(M / BM) * (N_DIM / BN), 256, 0, stream>>>(xb, wb, b, out);
}

// Round 2
// 324.160 us; speedup vs baseline: 1.2530x; 1.2530x over previous
//
#include <hip/hip_runtime.h>
#include <hip/hip_bf16.h>

#define K_DIM 4096
#define N_DIM 4096
#define R_DIM 16
#define SCALING_F 2.0f

#define BM 256
#define BN 256
#define BK 64   // bf16 elems per K-tile; 128 bytes per LDS row

typedef __attribute__((ext_vector_type(8))) short bf16x8;
typedef __attribute__((ext_vector_type(4))) float f32x4;

__device__ __forceinline__ ushort f2bf(float f) {
  union { float f; unsigned u; } v; v.f = f;
  unsigned u = v.u;
  u += 0x7FFF + ((u >> 16) & 1);   // round-to-nearest-even
  return (ushort)(u >> 16);
}

// ---- pre-pass 1: x (fp32) -> bf16 ----
__global__ void convert_x_kernel(const float* __restrict__ x,
                                 ushort* __restrict__ xb, long n4) {
  long i = (long)blockIdx.x * blockDim.x + threadIdx.x;
  long stride = (long)gridDim.x * blockDim.x;
  for (; i < n4; i += stride) {
    long idx = i * 4;
    float4 v = *(const float4*)(x + idx);
    ushort4 o;
    o.x = f2bf(v.x); o.y = f2bf(v.y); o.z = f2bf(v.z); o.w = f2bf(v.w);
    *(ushort4*)(xb + idx) = o;
  }
}

// ---- pre-pass 2: W_eff = W + 2.0 * (lora_B @ lora_A), cast to bf16 ----
__global__ void fold_w_kernel(const float* __restrict__ W,
                              const float* __restrict__ A,
                              const float* __restrict__ Bl,
                              ushort* __restrict__ wb) {
  int o = blockIdx.x;
  float breg[R_DIM];
#pragma unroll
  for (int r = 0; r < R_DIM; ++r) breg[r] = Bl[o * R_DIM + r] * SCALING_F;
  for (int d0 = threadIdx.x * 4; d0 < K_DIM; d0 += blockDim.x * 4) {
    float4 w = *(const float4*)(W + (size_t)o * K_DIM + d0);
    float a0 = w.x, a1 = w.y, a2 = w.z, a3 = w.w;
#pragma unroll
    for (int r = 0; r < R_DIM; ++r) {
      float4 a = *(const float4*)(A + (size_t)r * K_DIM + d0);
      a0 += breg[r] * a.x; a1 += breg[r] * a.y;
      a2 += breg[r] * a.z; a3 += breg[r] * a.w;
    }
    ushort4 ob;
    ob.x = f2bf(a0); ob.y = f2bf(a1); ob.z = f2bf(a2); ob.w = f2bf(a3);
    *(ushort4*)(wb + (size_t)o * K_DIM + d0) = ob;
  }
}

// ============================ 256x256 8-phase GEMM ============================
// 8 waves (2M x 4N), per-wave 128x64 output, acc[8][4] f32x4.
// LDS 128 KiB: A buf0 [0,32K) buf1 [32K,64K); B buf0 [64K,96K) buf1 [96K,128K).
// Tile layout per buffer: row-major 256 rows x 128 B, XOR-swizzled columns:
//   LDS[row][cb] holds G[row][cb ^ ((row&7)<<4)]  (16B-granular involution).
// Staged via inverse-swizzled GLOBAL source + linear global_load_lds dest.
// Phase/stage/wait schedule (ledger-verified race-free, vmcnt(6) at ph4/ph8):
//   ph1: read all B + A[m0-3]k0 (buf0) | stage Ao(t+1)->buf1 | MFMA m0-3 k0
//   ph2: read A[m0-3]k1               | stage B0(t+2)->buf0 | MFMA m0-3 k1
//   ph3: read A[m4-7]k0               | stage B1(t+2)->buf0 | MFMA m4-7 k0
//   ph4: read A[m4-7]k1               | stage Ae(t+2)->buf0 | MFMA, vmcnt(6)
//   ph5-8: same on buf1/tile t+1, staging Ao(t+2),B0,B1,Ae(t+3), vmcnt(6)

#define RS 8192L  // global row stride bytes (K_DIM * 2)

#define GLOAD(SRC, LOFF)                                                    \
  __builtin_amdgcn_global_load_lds(                                         \
      (const __attribute__((address_space(1))) void*)(SRC),                 \
      (__attribute__((address_space(3))) void*)(smem + (LOFF)), 16, 0, 0)

#define LDSA(BUF) ((BUF) * 32768)
#define LDSB(BUF) (65536 + (BUF) * 32768)

#define ST_A_EVEN(T, BUF) do {                                              \
    GLOAD(aS + (size_t)(T) * 128,            LDSA(BUF) + ldsDst);           \
    GLOAD(aS + (size_t)(T) * 128 + 128 * RS, LDSA(BUF) + 16384 + ldsDst); } while (0)
#define ST_A_ODD(T, BUF) do {                                               \
    GLOAD(aS + (size_t)(T) * 128 + 64 * RS,  LDSA(BUF) + 8192 + ldsDst);    \
    GLOAD(aS + (size_t)(T) * 128 + 192 * RS, LDSA(BUF) + 24576 + ldsDst); } while (0)
#define ST_B_H0(T, BUF) do {                                                \
    GLOAD(bS + (size_t)(T) * 128,            LDSB(BUF) + ldsDst);           \
    GLOAD(bS + (size_t)(T) * 128 + 64 * RS,  LDSB(BUF) + 8192 + ldsDst); } while (0)
#define ST_B_H1(T, BUF) do {                                                \
    GLOAD(bS + (size_t)(T) * 128 + 128 * RS, LDSB(BUF) + 16384 + ldsDst);   \
    GLOAD(bS + (size_t)(T) * 128 + 192 * RS, LDSB(BUF) + 24576 + ldsDst); } while (0)

#define LDA(M, CK, BUF) (*(const bf16x8*)(smem + LDSA(BUF) + aRd + (M) * 2048 + (CK)))
#define LDB(N, CK, BUF) (*(const bf16x8*)(smem + LDSB(BUF) + bRd + (N) * 2048 + (CK)))

#define MFMA16(MB, KK) do {                                                 \
    _Pragma("unroll") for (int mm = 0; mm < 4; ++mm)                        \
      _Pragma("unroll") for (int nn = 0; nn < 4; ++nn)                      \
        acc[(MB) + mm][nn] = __builtin_amdgcn_mfma_f32_16x16x32_bf16(       \
            afr[mm], bfr[nn][KK], acc[(MB) + mm][nn], 0, 0, 0); } while (0)

#define PH_OPEN()  __builtin_amdgcn_s_barrier(); __builtin_amdgcn_s_setprio(1)
#define PH_CLOSE() __builtin_amdgcn_s_setprio(0); __builtin_amdgcn_s_barrier()

__global__ __launch_bounds__(512, 2) void gemm_lora_kernel(
    const ushort* __restrict__ Ab, const ushort* __restrict__ Bb,
    const float* __restrict__ bias, float* __restrict__ C) {
  __shared__ char smem[131072];

  const int tid = threadIdx.x;
  const int wave = tid >> 6, lane = tid & 63;
  const int wm = wave >> 2, wn = wave & 3;
  const int fr = lane & 15, fq = lane >> 4;

  // XCD-aware mapping: XCD x owns bm in [4x,4x+4); bn sweeps. grid=512 (%8==0).
  const int bid = blockIdx.x;
  const int bm = ((bid & 7) << 2) + ((bid >> 3) & 3);
  const int bn = bid >> 5;

  // staging source (inverse-swizzled global addresses, 16B chunks)
  const int trow = tid >> 3;                                // 0..63
  const int tswz = ((tid & 7) << 4) ^ ((trow & 7) << 4);    // chunk permute in-row
  const char* aS = (const char*)Ab + (size_t)(bm * BM + trow) * RS + tswz;
  const char* bS = (const char*)Bb + (size_t)(bn * BN + trow) * RS + tswz;
  const int ldsDst = tid << 4;

  // swizzled ds_read column offsets
  const int sa  = (fr & 7) << 4;
  const int cK0 = (fq << 4) ^ sa;
  const int cK1 = (64 | (fq << 4)) ^ sa;
  const int aRd = ((wm << 7) + fr) << 7;   // (wm*128 + fr) * 128 B
  const int bRd = ((wn << 6) + fr) << 7;   // (wn*64  + fr) * 128 B

  f32x4 acc[8][4];
#pragma unroll
  for (int m = 0; m < 8; ++m)
#pragma unroll
    for (int n = 0; n < 4; ++n) acc[m][n] = (f32x4){0.f, 0.f, 0.f, 0.f};
  bf16x8 afr[4], bfr[4][2];

  // prologue: tile0 -> buf0 (B0,B1,Ae,Ao); tile1 -> buf1 (B0,B1,Ae). 14 loads.
  ST_B_H0(0, 0); ST_B_H1(0, 0); ST_A_EVEN(0, 0); ST_A_ODD(0, 0);
  ST_B_H0(1, 1); ST_B_H1(1, 1); ST_A_EVEN(1, 1);
  asm volatile("s_waitcnt vmcnt(6)" ::: "memory");  // tile0 fully landed
  __builtin_amdgcn_s_barrier();

  const int NIT = K_DIM / (2 * BK);  // 32
#pragma unroll 1
  for (int i = 0; i < NIT; ++i) {
    const int t1 = 2 * i + 1, t2 = 2 * i + 2, t3 = 2 * i + 3;
    const bool last = (i == NIT - 1);

    // ---- phase 1: buf0, m0-3, k0 (+ all 8 B frags) ----
#pragma unroll
    for (int n = 0; n < 4; ++n) { bfr[n][0] = LDB(n, cK0, 0); bfr[n][1] = LDB(n, cK1, 0); }
#pragma unroll
    for (int m = 0; m < 4; ++m) afr[m] = LDA(m, cK0, 0);
    ST_A_ODD(t1, 1);
    PH_OPEN();  MFMA16(0, 0);  PH_CLOSE();

    // ---- phase 2: buf0, m0-3, k1 ----
#pragma unroll
    for (int m = 0; m < 4; ++m) afr[m] = LDA(m, cK1, 0);
    if (!last) ST_B_H0(t2, 0);
    PH_OPEN();  MFMA16(0, 1);  PH_CLOSE();

    // ---- phase 3: buf0, m4-7, k0 ----
#pragma unroll
    for (int m = 0; m < 4; ++m) afr[m] = LDA(m + 4, cK0, 0);
    if (!last) ST_B_H1(t2, 0);
    PH_OPEN();  MFMA16(4, 0);  PH_CLOSE();

    // ---- phase 4: buf0, m4-7, k1 ; K-tile wait ----
#pragma unroll
    for (int m = 0; m < 4; ++m) afr[m] = LDA(m + 4, cK1, 0);
    if (!last) ST_A_EVEN(t2, 0);
    __builtin_amdgcn_s_barrier();
    __builtin_amdgcn_s_setprio(1);
    MFMA16(4, 1);
    __builtin_amdgcn_s_setprio(0);
    if (last) asm volatile("s_waitcnt vmcnt(0)" ::: "memory");
    else      asm volatile("s_waitcnt vmcnt(6)" ::: "memory");
    __builtin_amdgcn_s_barrier();

    // ---- phase 5: buf1, m0-3, k0 (+ all 8 B frags) ----
#pragma unroll
    for (int n = 0; n < 4; ++n) { bfr[n][0] = LDB(n, cK0, 1); bfr[n][1] = LDB(n, cK1, 1); }
#pragma unroll
    for (int m = 0; m < 4; ++m) afr[m] = LDA(m, cK0, 1);
    if (!last) ST_A_ODD(t2, 0);
    PH_OPEN();  MFMA16(0, 0);  PH_CLOSE();

    // ---- phase 6: buf1, m0-3, k1 ----
#pragma unroll
    for (int m = 0; m < 4; ++m) afr[m] = LDA(m, cK1, 1);
    if (!last) ST_B_H0(t3, 1);
    PH_OPEN();  MFMA16(0, 1);  PH_CLOSE();

    // ---- phase 7: buf1, m4-7, k0 ----
#pragma unroll
    for (int m = 0; m < 4; ++m) afr[m] = LDA(m + 4, cK0, 1);
    if (!last) ST_B_H1(t3, 1);
    PH_OPEN();  MFMA16(4, 0);  PH_CLOSE();

    // ---- phase 8: buf1, m4-7, k1 ; K-tile wait ----
#pragma unroll
    for (int m = 0; m < 4; ++m) afr[m] = LDA(m + 4, cK1, 1);
    if (!last) ST_A_EVEN(t3, 1);
    __builtin_amdgcn_s_barrier();
    __builtin_amdgcn_s_setprio(1);
    MFMA16(4, 1);
    __builtin_amdgcn_s_setprio(0);
    if (!last) {
      asm volatile("s_waitcnt vmcnt(6)" ::: "memory");
      __builtin_amdgcn_s_barrier();
    }
  }

  // epilogue: C/D layout col=lane&15, row=(lane>>4)*4+reg  [m89/m91]
  const int ccol0 = bn * BN + wn * 64 + fr;
  float bv[4];
#pragma unroll
  for (int n = 0; n < 4; ++n) bv[n] = bias[ccol0 + n * 16];
  const int crow0 = bm * BM + wm * 128 + fq * 4;
#pragma unroll
  for (int m = 0; m < 8; ++m)
#pragma unroll
    for (int n = 0; n < 4; ++n)
#pragma unroll
      for (int v = 0; v < 4; ++v) {
        int row = crow0 + m * 16 + v;
        C[(size_t)row * N_DIM + ccol0 + n * 16] = acc[m][n][v] + bv[n];
      }
}

extern "C" void kernel_launch(void* const* d_in, const int* in_sizes, int n_in,
                              void* d_out, int out_size, void* d_ws, size_t ws_size,
                              hipStream_t stream) {
  const float* x  = (const float*)d_in[0];   // [M, K]
  const float* W  = (const float*)d_in[1];   // [N, K]
  const float* b  = (const float*)d_in[2];   // [N]
  const float* lA = (const float*)d_in[3];   // [R, K]
  const float* lB = (const float*)d_in[4];   // [N, R]
  float* out = (float*)d_out;                // [M, N]

  const int M = in_sizes[0] / K_DIM;  // 8192

  ushort* xb = (ushort*)d_ws;                 // 64 MB
  ushort* wb = xb + (size_t)M * K_DIM;        // 32 MB

  long n4 = (long)M * K_DIM / 4;
  convert_x_kernel<<<2048, 256, 0, stream>>>(x, xb, n4);
  fold_w_kernel<<<N_DIM, 256, 0, stream>>>(W, lA, lB, wb);
  gemm_lora_kernel<<<(M / BM) * (N_DIM / BN), 512, 0, stream>>>(xb, wb, b, out);
}